// Round 9
// baseline (406.354 us; speedup 1.0000x reference)
//
#include <hip/hip_runtime.h>

#define RES 256
#define NV 6890
#define CAP 16                          // max verts per 8^3 cell (mean 0.39)
#define NCELL (32*32*32)
#define NTILE (32*32*16)                // 8x8x16-voxel tiles
#define TCAP 64                         // max candidates per tile (mean 3.4)
#define SEM_ELEMS (RES*RES*RES*3)

typedef float f32x4 __attribute__((ext_vector_type(4)));

// ---------------------------------------------------------------------------
// Kernel 1: zero cell counters + tile counters (ws is poisoned every call).
// ---------------------------------------------------------------------------
__global__ void svox_zero(int* __restrict__ counts, int* __restrict__ tcounts) {
    int i = blockIdx.x * blockDim.x + threadIdx.x;
    if (i < NCELL) counts[i] = 0;
    if (i < NTILE) tcounts[i] = 0;
}

// ---------------------------------------------------------------------------
// Kernel 2: bucket vertices into 8^3 cells. Packed record:
//   rec0 = (vx, vy, vz, bitcast((cx+8)<<20 | (cy+8)<<10 | (cz+8)))
//   rec1 = (c0, c1, c2, 0)
// ---------------------------------------------------------------------------
__global__ void svox_bucket(const float* __restrict__ verts,
                            const float* __restrict__ codes,
                            int* __restrict__ counts,
                            f32x4* __restrict__ lists) {
    int n = blockIdx.x * blockDim.x + threadIdx.x;
    if (n >= NV) return;
    float vx = verts[3 * n + 0], vy = verts[3 * n + 1], vz = verts[3 * n + 2];
    int cx = (int)floorf((vx + 0.5f) * 256.0f);
    int cy = (int)floorf((vy + 0.5f) * 256.0f);
    int cz = (int)floorf((vz + 0.5f) * 256.0f);
    int px = min(max(cx + 8, 0), 1023);
    int py = min(max(cy + 8, 0), 1023);
    int pz = min(max(cz + 8, 0), 1023);
    int bx = min(max(cx >> 3, 0), 31);
    int by = min(max(cy >> 3, 0), 31);
    int bz = min(max(cz >> 3, 0), 31);
    int cell = (bx << 10) | (by << 5) | bz;
    int slot = atomicAdd(&counts[cell], 1);
    if (slot < CAP) {
        int pk = (px << 20) | (py << 10) | pz;
        f32x4 r0 = {vx, vy, vz, __int_as_float(pk)};
        f32x4 r1 = {codes[3 * n + 0], codes[3 * n + 1], codes[3 * n + 2], 0.0f};
        lists[(cell * CAP + slot) * 2 + 0] = r0;
        lists[(cell * CAP + slot) * 2 + 1] = r1;
    }
}

// ---------------------------------------------------------------------------
// Kernel 3: per-tile exact merged candidate list. Tile (bx,by,bzp) covers
// voxels x,y in [8b, 8b+7], z in [16bzp, 16bzp+15]; a vertex can touch it
// iff its center is in [8bx-3, 8bx+10] x [8by-3, 8by+10] x [16bzp-3,16bzp+18].
// Single writer per tile: no atomics. 16384 threads.
// ---------------------------------------------------------------------------
__global__ void svox_build_tiles(const int* __restrict__ counts,
                                 const f32x4* __restrict__ lists,
                                 int* __restrict__ tcounts,
                                 f32x4* __restrict__ tlists) {
    int i = blockIdx.x * blockDim.x + threadIdx.x;
    if (i >= NTILE) return;
    int bzp = i & 15, by = (i >> 4) & 31, bx = i >> 9;
    int xlo = 8 * bx - 3,  xhi = 8 * bx + 10;
    int ylo = 8 * by - 3,  yhi = 8 * by + 10;
    int zlo = 16 * bzp - 3, zhi = 16 * bzp + 18;
    int n = 0;
    int tbase = i * TCAP * 2;
    int cx0 = max(bx - 1, 0), cx1 = min(bx + 1, 31);
    int cy0 = max(by - 1, 0), cy1 = min(by + 1, 31);
    int cz0 = max(2 * bzp - 1, 0), cz1 = min(2 * bzp + 2, 31);
    for (int cx = cx0; cx <= cx1; ++cx)
    for (int cy = cy0; cy <= cy1; ++cy)
    for (int cz = cz0; cz <= cz1; ++cz) {
        int cell = (cx << 10) | (cy << 5) | cz;
        int cnt = min(counts[cell], CAP);
        int gb = cell * CAP;
        for (int j = 0; j < cnt; ++j) {
            f32x4 r0 = lists[(gb + j) * 2 + 0];
            int pk = __float_as_int(r0.w);
            int vcx = ((pk >> 20) & 1023) - 8;
            int vcy = ((pk >> 10) & 1023) - 8;
            int vcz = (pk & 1023) - 8;
            if (vcx < xlo || vcx > xhi || vcy < ylo || vcy > yhi ||
                vcz < zlo || vcz > zhi) continue;
            if (n < TCAP) {
                tlists[tbase + n * 2 + 0] = r0;
                tlists[tbase + n * 2 + 1] = lists[(gb + j) * 2 + 1];
                ++n;
            }
        }
    }
    tcounts[i] = n;
}

// ---------------------------------------------------------------------------
// Kernel 4: gather. One 256-thread block per 8x8x16 tile; every lane reads
// the SAME tile list (broadcast loads, uniform trip count, no divergent
// loops, no LDS, no barriers). Each thread owns one z-quad; per-(x,y) row the
// block writes 192B sem (3 full lines) + 64B wsum (1 line): no partial lines.
// ---------------------------------------------------------------------------
__global__ void __launch_bounds__(256)
svox_gather(const float* __restrict__ occ,
            const int* __restrict__ tcounts,
            const f32x4* __restrict__ tlists,
            f32x4* __restrict__ sem4,
            f32x4* __restrict__ wsum4) {
    int bzp = blockIdx.x, by = blockIdx.y, bx = blockIdx.z;
    int tile = (bx << 9) | (by << 4) | bzp;
    int n = tcounts[tile];                       // wave-uniform broadcast

    int tid = threadIdx.x;
    int x  = (bx << 3) + (tid >> 5);
    int y  = (by << 3) + ((tid >> 2) & 7);
    int z0 = (bzp << 4) + ((tid & 3) << 2);
    int lin0 = (((x << 8) + y) << 8) + z0;
    int t = lin0 >> 2;

    float acc[4][4];
#pragma unroll
    for (int q = 0; q < 4; ++q) {
        acc[q][0] = 0.f; acc[q][1] = 0.f; acc[q][2] = 0.f; acc[q][3] = 0.f;
    }

    if (n > 0) {
        const float inv = 1.0f / 256.0f;
        float fx  = ((float)x  + 0.5f) * inv - 0.5f;
        float fy  = ((float)y  + 0.5f) * inv - 0.5f;
        float fz0 = ((float)z0 + 0.5f) * inv - 0.5f;

        const f32x4 o4 = *(const f32x4*)&occ[lin0];
        float occv[4] = {o4.x, o4.y, o4.z, o4.w};

        int base = tile * TCAP * 2;
        for (int j = 0; j < n; ++j) {            // uniform trip count
            f32x4 r0 = tlists[base + j * 2 + 0]; // broadcast
            int pk = __float_as_int(r0.w);
            int cxb = (pk >> 20) & 1023;         // cx + 8
            int cyb = (pk >> 10) & 1023;
            int czb =  pk        & 1023;
            unsigned dxi = (unsigned)(x  + 11 - cxb);   // x - cx + 3
            unsigned dyi = (unsigned)(y  + 11 - cyb);
            unsigned dzq = (unsigned)(z0 + 14 - czb);   // z0 - cz + 6
            if (dxi > 6u || dyi > 6u || dzq > 9u) continue;

            f32x4 r1 = tlists[base + j * 2 + 1];
            float dx = fx - r0.x, dy = fy - r0.y;
            float exy = __expf(-8192.0f * (dx * dx + dy * dy));
            int czr = czb - 8;
#pragma unroll
            for (int q = 0; q < 4; ++q) {
                unsigned dzi = (unsigned)(z0 + q - czr + 3);
                if (dzi > 6u) continue;
                if (occv[q] <= 0.0f) continue;
                float dz = fz0 + (float)q * inv - r0.z;
                float w = exy * __expf(-8192.0f * dz * dz);
                acc[q][0] += w * r1.x;
                acc[q][1] += w * r1.y;
                acc[q][2] += w * r1.z;
                acc[q][3] += w;
            }
        }
    }

    f32x4 s0 = {acc[0][0], acc[0][1], acc[0][2], acc[1][0]};
    f32x4 s1 = {acc[1][1], acc[1][2], acc[2][0], acc[2][1]};
    f32x4 s2 = {acc[2][2], acc[3][0], acc[3][1], acc[3][2]};
    f32x4 sw = {0.001f + acc[0][3], 0.001f + acc[1][3],
                0.001f + acc[2][3], 0.001f + acc[3][3]};
    sem4[t * 3 + 0] = s0;
    sem4[t * 3 + 1] = s1;
    sem4[t * 3 + 2] = s2;
    wsum4[t] = sw;
}

extern "C" void kernel_launch(void* const* d_in, const int* in_sizes, int n_in,
                              void* d_out, int out_size, void* d_ws, size_t ws_size,
                              hipStream_t stream) {
    const float* verts = (const float*)d_in[0];   // (6890,3) f32
    const float* codes = (const float*)d_in[1];   // (6890,3) f32
    const float* occ   = (const float*)d_in[2];   // (256,256,256) f32
    // d_in[3] = smpl_faces (unused by the reference computation)

    f32x4* sem4  = (f32x4*)d_out;                       // 12,582,912 f32x4
    f32x4* wsum4 = (f32x4*)((float*)d_out + SEM_ELEMS); // 4,194,304 f32x4

    int*   counts  = (int*)d_ws;                        // 128 KB
    f32x4* lists   = (f32x4*)(counts + NCELL);          // 16 MB
    int*   tcounts = (int*)(lists + NCELL * CAP * 2);   // 64 KB
    f32x4* tlists  = (f32x4*)(tcounts + NTILE);         // 32 MB

    svox_zero<<<(NCELL + 255) / 256, 256, 0, stream>>>(counts, tcounts);
    svox_bucket<<<(NV + 255) / 256, 256, 0, stream>>>(verts, codes, counts, lists);
    svox_build_tiles<<<(NTILE + 255) / 256, 256, 0, stream>>>(counts, lists,
                                                              tcounts, tlists);
    dim3 grid(16, 32, 32);                              // (bzp, by, bx)
    svox_gather<<<grid, 256, 0, stream>>>(occ, tcounts, tlists, sem4, wsum4);
}

// Round 10
// 330.554 us; speedup vs baseline: 1.2293x; 1.2293x over previous
//
#include <hip/hip_runtime.h>

#define RES 256
#define NV 6890
#define NXY (32*32)                     // 2-D xy cells (8x8 voxels each)
#define XCAP 64                         // per xy-cell capacity (mean 6.7, Poisson tail ~1e-42)
#define SEM_ELEMS (RES*RES*RES*3)

typedef float f32x4 __attribute__((ext_vector_type(4)));

// ---------------------------------------------------------------------------
// Kernel 1: zero the xy-cell counters (d_ws is re-poisoned before every call).
// ---------------------------------------------------------------------------
__global__ void svox_zero(int* __restrict__ counts) {
    int i = blockIdx.x * blockDim.x + threadIdx.x;
    if (i < NXY) counts[i] = 0;
}

// ---------------------------------------------------------------------------
// Kernel 2: bucket vertices by (cx>>3, cy>>3). Packed record:
//   rec0 = (vx, vy, vz, bitcast((cx+8)<<20 | (cy+8)<<10 | (cz+8)))
//   rec1 = (c0, c1, c2, 0)
// Biased centers clamped to [0,1023] can never pass |voxel-center|<=3, so
// edge clamping is value-exact.
// ---------------------------------------------------------------------------
__global__ void svox_bucket_xy(const float* __restrict__ verts,
                               const float* __restrict__ codes,
                               int* __restrict__ counts,
                               f32x4* __restrict__ lists) {
    int n = blockIdx.x * blockDim.x + threadIdx.x;
    if (n >= NV) return;
    float vx = verts[3 * n + 0], vy = verts[3 * n + 1], vz = verts[3 * n + 2];
    int cx = (int)floorf((vx + 0.5f) * 256.0f);
    int cy = (int)floorf((vy + 0.5f) * 256.0f);
    int cz = (int)floorf((vz + 0.5f) * 256.0f);
    int px = min(max(cx + 8, 0), 1023);
    int py = min(max(cy + 8, 0), 1023);
    int pz = min(max(cz + 8, 0), 1023);
    int bx = min(max(cx >> 3, 0), 31);
    int by = min(max(cy >> 3, 0), 31);
    int cell = (bx << 5) | by;
    int slot = atomicAdd(&counts[cell], 1);
    if (slot < XCAP) {
        int pk = (px << 20) | (py << 10) | pz;
        f32x4 r0 = {vx, vy, vz, __int_as_float(pk)};
        f32x4 r1 = {codes[3 * n + 0], codes[3 * n + 1], codes[3 * n + 2], 0.0f};
        lists[(cell * XCAP + slot) * 2 + 0] = r0;
        lists[(cell * XCAP + slot) * 2 + 1] = r1;
    }
}

// ---------------------------------------------------------------------------
// Kernel 3: gather. One WAVE per (x,y) column (256 z-voxels); lane owns a
// z-quad. Candidates (<=4 xy-cells, wave-uniform list) are scanned with
// scalar-branch rejection on the uniform xy window test; z work is per-lane
// predication. Sem output transposed through a wave-private LDS slice so all
// global store instructions are 64-lane CONTIGUOUS (1 KB each, fill-like).
// ---------------------------------------------------------------------------
__global__ void __launch_bounds__(256)
svox_gather(const float* __restrict__ occ,
            const int* __restrict__ counts,
            const f32x4* __restrict__ lists,
            f32x4* __restrict__ sem4,
            f32x4* __restrict__ wsum4) {
    __shared__ f32x4 lds[4][192];                 // 3 KB per wave

    int lane = threadIdx.x & 63;
    int wid  = threadIdx.x >> 6;
    int col  = __builtin_amdgcn_readfirstlane((int)(blockIdx.x * 4 + wid));
    int x = col >> 8, y = col & 255;
    int z0 = lane << 2;

    int smbase = col * 192;                       // sem4 f32x4 base of column
    int wsbase = col << 6;                        // wsum4 base of column

    // candidate cells for xy window +-3
    int cx0 = max(x - 3, 0) >> 3, cx1 = min(x + 3, 255) >> 3;
    int cy0 = max(y - 3, 0) >> 3, cy1 = min(y + 3, 255) >> 3;

    int tot = 0;
    for (int cx = cx0; cx <= cx1; ++cx)
        for (int cy = cy0; cy <= cy1; ++cy)
            tot += counts[(cx << 5) | cy];

    if (tot == 0) {                               // ~55% of columns
        f32x4 z = {0.f, 0.f, 0.f, 0.f};
        f32x4 sw = {0.001f, 0.001f, 0.001f, 0.001f};
        sem4[smbase + lane]       = z;
        sem4[smbase + 64 + lane]  = z;
        sem4[smbase + 128 + lane] = z;
        wsum4[wsbase + lane]      = sw;
        return;
    }

    float acc[4][4];
#pragma unroll
    for (int q = 0; q < 4; ++q) {
        acc[q][0] = 0.f; acc[q][1] = 0.f; acc[q][2] = 0.f; acc[q][3] = 0.f;
    }

    const float inv = 1.0f / 256.0f;
    float fx  = ((float)x  + 0.5f) * inv - 0.5f;
    float fy  = ((float)y  + 0.5f) * inv - 0.5f;
    float fz0 = ((float)z0 + 0.5f) * inv - 0.5f;

    int lin0 = (col << 8) + z0;
    const f32x4 o4 = *(const f32x4*)&occ[lin0];   // 16B/lane, contiguous 1KB/wave
    float occv[4] = {o4.x, o4.y, o4.z, o4.w};

    for (int cx = cx0; cx <= cx1; ++cx)
    for (int cy = cy0; cy <= cy1; ++cy) {
        int cell = (cx << 5) | cy;
        int cn = min(counts[cell], XCAP);
        int base = cell * XCAP * 2;
        for (int j = 0; j < cn; ++j) {
            f32x4 r0 = lists[base + 2 * j];       // wave-uniform address
            int pk = __float_as_int(r0.w);
            int cxb = (pk >> 20) & 1023;          // cx + 8
            int cyb = (pk >> 10) & 1023;
            int czb =  pk        & 1023;
            // wave-uniform xy window test -> scalar branch
            if ((unsigned)(x + 11 - cxb) > 6u || (unsigned)(y + 11 - cyb) > 6u)
                continue;
            f32x4 r1 = lists[base + 2 * j + 1];
            float dx = fx - r0.x, dy = fy - r0.y;
            float exy = __expf(-8192.0f * (dx * dx + dy * dy));
            // per-lane z-quad overlap: z0 - cz + 6 in [0,9]
            if ((unsigned)(z0 + 14 - czb) <= 9u) {
#pragma unroll
                for (int q = 0; q < 4; ++q) {
                    unsigned dzi = (unsigned)(z0 + q + 11 - czb);  // z - cz + 3
                    if (dzi > 6u) continue;
                    if (occv[q] <= 0.0f) continue;
                    float dz = fz0 + (float)q * inv - r0.z;
                    float w = exy * __expf(-8192.0f * dz * dz);
                    acc[q][0] += w * r1.x;
                    acc[q][1] += w * r1.y;
                    acc[q][2] += w * r1.z;
                    acc[q][3] += w;
                }
            }
        }
    }

    // ---- store-transpose: 12 sem floats/lane -> contiguous 1KB store insts ----
    f32x4* L = lds[wid];
    f32x4 p0 = {acc[0][0], acc[0][1], acc[0][2], acc[1][0]};
    f32x4 p1 = {acc[1][1], acc[1][2], acc[2][0], acc[2][1]};
    f32x4 p2 = {acc[2][2], acc[3][0], acc[3][1], acc[3][2]};
    L[3 * lane + 0] = p0;
    L[3 * lane + 1] = p1;
    L[3 * lane + 2] = p2;
    __builtin_amdgcn_wave_barrier();              // intra-wave; lgkmcnt by compiler
    sem4[smbase + lane]       = L[lane];
    sem4[smbase + 64 + lane]  = L[64 + lane];
    sem4[smbase + 128 + lane] = L[128 + lane];
    f32x4 sw = {0.001f + acc[0][3], 0.001f + acc[1][3],
                0.001f + acc[2][3], 0.001f + acc[3][3]};
    wsum4[wsbase + lane] = sw;
}

extern "C" void kernel_launch(void* const* d_in, const int* in_sizes, int n_in,
                              void* d_out, int out_size, void* d_ws, size_t ws_size,
                              hipStream_t stream) {
    const float* verts = (const float*)d_in[0];   // (6890,3) f32
    const float* codes = (const float*)d_in[1];   // (6890,3) f32
    const float* occ   = (const float*)d_in[2];   // (256,256,256) f32
    // d_in[3] = smpl_faces (unused by the reference computation)

    f32x4* sem4  = (f32x4*)d_out;                       // 12,582,912 f32x4
    f32x4* wsum4 = (f32x4*)((float*)d_out + SEM_ELEMS); // 4,194,304 f32x4

    int*   counts = (int*)d_ws;                   // 4 KB
    f32x4* lists  = (f32x4*)(counts + 1024);      // 1024*64*2 f32x4 = 2 MB

    svox_zero<<<4, 256, 0, stream>>>(counts);
    svox_bucket_xy<<<(NV + 255) / 256, 256, 0, stream>>>(verts, codes, counts, lists);
    svox_gather<<<(RES * RES) / 4, 256, 0, stream>>>(occ, counts, lists, sem4, wsum4);
}

// Round 11
// 329.514 us; speedup vs baseline: 1.2332x; 1.0032x over previous
//
#include <hip/hip_runtime.h>

#define RES 256
#define NV 6890
#define NXY (32*32)                     // 2-D xy cells (8x8 voxels each)
#define XCAP 64                         // per xy-cell capacity (mean 6.7, Poisson tail ~1e-42)
#define SEM_ELEMS (RES*RES*RES*3)

typedef float f32x4 __attribute__((ext_vector_type(4)));

// ---------------------------------------------------------------------------
// Kernel 1: zero the xy-cell counters (d_ws is re-poisoned before every call).
// ---------------------------------------------------------------------------
__global__ void svox_zero(int* __restrict__ counts) {
    int i = blockIdx.x * blockDim.x + threadIdx.x;
    if (i < NXY) counts[i] = 0;
}

// ---------------------------------------------------------------------------
// Kernel 2: bucket vertices by (cx>>3, cy>>3). Packed record:
//   rec0 = (vx, vy, vz, bitcast((cx+8)<<20 | (cy+8)<<10 | (cz+8)))
//   rec1 = (c0, c1, c2, 0)
// Biased centers clamped to [0,1023] can never pass |voxel-center|<=3, so
// edge clamping is value-exact.
// ---------------------------------------------------------------------------
__global__ void svox_bucket_xy(const float* __restrict__ verts,
                               const float* __restrict__ codes,
                               int* __restrict__ counts,
                               f32x4* __restrict__ lists) {
    int n = blockIdx.x * blockDim.x + threadIdx.x;
    if (n >= NV) return;
    float vx = verts[3 * n + 0], vy = verts[3 * n + 1], vz = verts[3 * n + 2];
    int cx = (int)floorf((vx + 0.5f) * 256.0f);
    int cy = (int)floorf((vy + 0.5f) * 256.0f);
    int cz = (int)floorf((vz + 0.5f) * 256.0f);
    int px = min(max(cx + 8, 0), 1023);
    int py = min(max(cy + 8, 0), 1023);
    int pz = min(max(cz + 8, 0), 1023);
    int bx = min(max(cx >> 3, 0), 31);
    int by = min(max(cy >> 3, 0), 31);
    int cell = (bx << 5) | by;
    int slot = atomicAdd(&counts[cell], 1);
    if (slot < XCAP) {
        int pk = (px << 20) | (py << 10) | pz;
        f32x4 r0 = {vx, vy, vz, __int_as_float(pk)};
        f32x4 r1 = {codes[3 * n + 0], codes[3 * n + 1], codes[3 * n + 2], 0.0f};
        lists[(cell * XCAP + slot) * 2 + 0] = r0;
        lists[(cell * XCAP + slot) * 2 + 1] = r1;
    }
}

// ---------------------------------------------------------------------------
// Kernel 3: gather. One WAVE per (x,y) column (256 z-voxels); lane owns a
// z-quad. Candidates (<=4 xy-cells, wave-uniform list) scanned with scalar
// rejection on the uniform xy window; z work is per-lane predication. Sem
// transposed through a wave-private LDS slice so all global stores are
// 64-lane contiguous (1 KB per instruction, 16 full lines) -> safe for
// NONTEMPORAL stores (fill-like: no L2 allocation of write-once lines).
// ---------------------------------------------------------------------------
__global__ void __launch_bounds__(256)
svox_gather(const float* __restrict__ occ,
            const int* __restrict__ counts,
            const f32x4* __restrict__ lists,
            f32x4* __restrict__ sem4,
            f32x4* __restrict__ wsum4) {
    __shared__ f32x4 lds[4][192];                 // 3 KB per wave

    int lane = threadIdx.x & 63;
    int wid  = threadIdx.x >> 6;
    int col  = __builtin_amdgcn_readfirstlane((int)(blockIdx.x * 4 + wid));
    int x = col >> 8, y = col & 255;
    int z0 = lane << 2;

    int smbase = col * 192;                       // sem4 f32x4 base of column
    int wsbase = col << 6;                        // wsum4 base of column

    // candidate cells for xy window +-3
    int cx0 = max(x - 3, 0) >> 3, cx1 = min(x + 3, 255) >> 3;
    int cy0 = max(y - 3, 0) >> 3, cy1 = min(y + 3, 255) >> 3;

    int tot = 0;
    for (int cx = cx0; cx <= cx1; ++cx)
        for (int cy = cy0; cy <= cy1; ++cy)
            tot += counts[(cx << 5) | cy];

    if (tot == 0) {                               // ~55% of columns
        f32x4 z = {0.f, 0.f, 0.f, 0.f};
        f32x4 sw = {0.001f, 0.001f, 0.001f, 0.001f};
        __builtin_nontemporal_store(z,  &sem4[smbase + lane]);
        __builtin_nontemporal_store(z,  &sem4[smbase + 64 + lane]);
        __builtin_nontemporal_store(z,  &sem4[smbase + 128 + lane]);
        __builtin_nontemporal_store(sw, &wsum4[wsbase + lane]);
        return;
    }

    float acc[4][4];
#pragma unroll
    for (int q = 0; q < 4; ++q) {
        acc[q][0] = 0.f; acc[q][1] = 0.f; acc[q][2] = 0.f; acc[q][3] = 0.f;
    }

    const float inv = 1.0f / 256.0f;
    float fx  = ((float)x  + 0.5f) * inv - 0.5f;
    float fy  = ((float)y  + 0.5f) * inv - 0.5f;
    float fz0 = ((float)z0 + 0.5f) * inv - 0.5f;

    int lin0 = (col << 8) + z0;
    const f32x4 o4 = __builtin_nontemporal_load((const f32x4*)&occ[lin0]);
    float occv[4] = {o4.x, o4.y, o4.z, o4.w};

    for (int cx = cx0; cx <= cx1; ++cx)
    for (int cy = cy0; cy <= cy1; ++cy) {
        int cell = (cx << 5) | cy;
        int cn = min(counts[cell], XCAP);
        int base = cell * XCAP * 2;
        for (int j = 0; j < cn; ++j) {
            f32x4 r0 = lists[base + 2 * j];       // wave-uniform address
            int pk = __float_as_int(r0.w);
            int cxb = (pk >> 20) & 1023;          // cx + 8
            int cyb = (pk >> 10) & 1023;
            int czb =  pk        & 1023;
            // wave-uniform xy window test -> scalar branch
            if ((unsigned)(x + 11 - cxb) > 6u || (unsigned)(y + 11 - cyb) > 6u)
                continue;
            f32x4 r1 = lists[base + 2 * j + 1];
            float dx = fx - r0.x, dy = fy - r0.y;
            float exy = __expf(-8192.0f * (dx * dx + dy * dy));
            // per-lane z-quad overlap: z0 - cz + 6 in [0,9]
            if ((unsigned)(z0 + 14 - czb) <= 9u) {
#pragma unroll
                for (int q = 0; q < 4; ++q) {
                    unsigned dzi = (unsigned)(z0 + q + 11 - czb);  // z - cz + 3
                    if (dzi > 6u) continue;
                    if (occv[q] <= 0.0f) continue;
                    float dz = fz0 + (float)q * inv - r0.z;
                    float w = exy * __expf(-8192.0f * dz * dz);
                    acc[q][0] += w * r1.x;
                    acc[q][1] += w * r1.y;
                    acc[q][2] += w * r1.z;
                    acc[q][3] += w;
                }
            }
        }
    }

    // ---- store-transpose: 12 sem floats/lane -> contiguous 1KB store insts ----
    f32x4* L = lds[wid];
    f32x4 p0 = {acc[0][0], acc[0][1], acc[0][2], acc[1][0]};
    f32x4 p1 = {acc[1][1], acc[1][2], acc[2][0], acc[2][1]};
    f32x4 p2 = {acc[2][2], acc[3][0], acc[3][1], acc[3][2]};
    L[3 * lane + 0] = p0;
    L[3 * lane + 1] = p1;
    L[3 * lane + 2] = p2;
    __builtin_amdgcn_wave_barrier();              // intra-wave; lgkmcnt by compiler
    f32x4 q0 = L[lane];
    f32x4 q1 = L[64 + lane];
    f32x4 q2 = L[128 + lane];
    __builtin_nontemporal_store(q0, &sem4[smbase + lane]);
    __builtin_nontemporal_store(q1, &sem4[smbase + 64 + lane]);
    __builtin_nontemporal_store(q2, &sem4[smbase + 128 + lane]);
    f32x4 sw = {0.001f + acc[0][3], 0.001f + acc[1][3],
                0.001f + acc[2][3], 0.001f + acc[3][3]};
    __builtin_nontemporal_store(sw, &wsum4[wsbase + lane]);
}

extern "C" void kernel_launch(void* const* d_in, const int* in_sizes, int n_in,
                              void* d_out, int out_size, void* d_ws, size_t ws_size,
                              hipStream_t stream) {
    const float* verts = (const float*)d_in[0];   // (6890,3) f32
    const float* codes = (const float*)d_in[1];   // (6890,3) f32
    const float* occ   = (const float*)d_in[2];   // (256,256,256) f32
    // d_in[3] = smpl_faces (unused by the reference computation)

    f32x4* sem4  = (f32x4*)d_out;                       // 12,582,912 f32x4
    f32x4* wsum4 = (f32x4*)((float*)d_out + SEM_ELEMS); // 4,194,304 f32x4

    int*   counts = (int*)d_ws;                   // 4 KB
    f32x4* lists  = (f32x4*)(counts + 1024);      // 1024*64*2 f32x4 = 2 MB

    svox_zero<<<4, 256, 0, stream>>>(counts);
    svox_bucket_xy<<<(NV + 255) / 256, 256, 0, stream>>>(verts, codes, counts, lists);
    svox_gather<<<(RES * RES) / 4, 256, 0, stream>>>(occ, counts, lists, sem4, wsum4);
}